// Round 12
// baseline (218.889 us; speedup 1.0000x reference)
//
#include <hip/hip_runtime.h>
#include <hip/hip_bf16.h>
#include <float.h>

#define B_ 64
#define H_ 1024
#define S_ 1024
#define V_ 50257
#define VPAD 50304    // 1572 * 32
#define L_ 3
#define G3H 3072      // 3*H
#define N_GATES 6144  // 2*3H fused gi|gh
#define KSPL_GRU 8    // K-split for GRU gates GEMM
#define KSPL_CAT 16   // K-split for concat GEMM

typedef __attribute__((ext_vector_type(8))) short short8v;  // 8 bf16 (4 VGPRs)
typedef __attribute__((ext_vector_type(4))) float f32x4;    // MFMA accumulator

// round-to-nearest f32 -> bf16 bits
__device__ __forceinline__ ushort rnd_bf16(float x) {
    uint u = __float_as_uint(x);
    return (ushort)((u + 0x7fffu + ((u >> 16) & 1u)) >> 16);
}

// exact split x = hi + lo (hi = truncated bf16, lo = rounded residual)
__device__ __forceinline__ void split_bf16(float x, ushort& hi, ushort& lo) {
    uint u = __float_as_uint(x);
    uint h = u & 0xffff0000u;
    hi = (ushort)(h >> 16);
    float r = x - __uint_as_float(h);
    uint ur = __float_as_uint(r);
    lo = (ushort)((ur + 0x7fffu + ((ur >> 16) & 1u)) >> 16);
}

// ---------------------------------------------------------------------------
// Generic M=64 bf16-MFMA GEMM, all-LDS inner loop (R9-best, unchanged):
// Cpart[ky][64][N] = A[64][K] x W[N][K]^T partials.
__global__ __launch_bounds__(256) void gemm_bf16_lds(
    const float* __restrict__ A0, const int* __restrict__ seq,
    const float* __restrict__ A1, int lda,
    const float* __restrict__ W0, const float* __restrict__ W1, int ldw,
    int Nhalf, float* __restrict__ Cpart, int N, int K) {
    __shared__ ushort AhL[2][64 * 64];
    __shared__ ushort AlL[2][64 * 64];
    __shared__ ushort WtL[2][64 * 64];  // 48 KB total

    int tid = threadIdx.x;
    int w = tid >> 6, l = tid & 63;
    int lr = l & 15;  // A row / W row within 16-tile
    int lk = l >> 4;  // k-subgroup 0..3

    int n0 = blockIdx.x * 64;
    const float* A = A0;
    const float* W = W0;
    const int* sq = seq;
    int ncol0 = n0;
    if (n0 >= Nhalf) { A = A1; W = W1; ncol0 = n0 - Nhalf; sq = nullptr; }

    int srow = tid >> 2;  // 0..63
    int sqk = tid & 3;    // 0..3
    const float* Asrc = A + (size_t)(sq ? sq[srow] : srow) * lda;
    const float* Wsrc = W + (size_t)(ncol0 + srow) * ldw;

    int kChunk = K / gridDim.y;
    int kBeg = blockIdx.y * kChunk;
    int nt = kChunk >> 6;  // 64-k tiles

    union SV { short8v v; ushort u[8]; };

    float4 rA[4], rW[4];
    auto load_regs = [&](int kt) {
        int kb = kBeg + kt * 64 + sqk * 16;
#pragma unroll
        for (int i = 0; i < 4; i++) {
            rA[i] = *(const float4*)&Asrc[kb + i * 4];
            rW[i] = *(const float4*)&Wsrc[kb + i * 4];
        }
    };
    auto write_lds = [&](int buf) {
        int s0 = (2 * sqk) ^ (srow & 7);
        int s1 = (2 * sqk + 1) ^ (srow & 7);
        int base = srow * 64;
        SV h0, h1, l0, l1, q0, q1;
        const float* fa = (const float*)&rA[0];
        const float* fw = (const float*)&rW[0];
#pragma unroll
        for (int j = 0; j < 8; j++) {
            split_bf16(fa[j], h0.u[j], l0.u[j]);
            split_bf16(fa[8 + j], h1.u[j], l1.u[j]);
            q0.u[j] = rnd_bf16(fw[j]);
            q1.u[j] = rnd_bf16(fw[8 + j]);
        }
        *(short8v*)&AhL[buf][base + s0 * 8] = h0.v;
        *(short8v*)&AhL[buf][base + s1 * 8] = h1.v;
        *(short8v*)&AlL[buf][base + s0 * 8] = l0.v;
        *(short8v*)&AlL[buf][base + s1 * 8] = l1.v;
        *(short8v*)&WtL[buf][base + s0 * 8] = q0.v;
        *(short8v*)&WtL[buf][base + s1 * 8] = q1.v;
    };

    f32x4 acc[4];
#pragma unroll
    for (int mt = 0; mt < 4; mt++) acc[mt] = (f32x4){0.f, 0.f, 0.f, 0.f};

    load_regs(0);
    write_lds(0);
    __syncthreads();

    int wrow = w * 16 + lr;  // block-local output col
    for (int kt = 0; kt < nt; kt++) {
        if (kt + 1 < nt) load_regs(kt + 1);  // fly under compute

        int cur = kt & 1;
#pragma unroll
        for (int ks = 0; ks < 2; ks++) {
            int slot = ks * 4 + lk;
            short8v wf = *(const short8v*)&WtL[cur][wrow * 64 + ((slot ^ (wrow & 7)) << 3)];
#pragma unroll
            for (int mt = 0; mt < 4; mt++) {
                int arow = mt * 16 + lr;
                int so = (slot ^ (arow & 7)) << 3;
                short8v ah = *(const short8v*)&AhL[cur][arow * 64 + so];
                short8v al = *(const short8v*)&AlL[cur][arow * 64 + so];
                acc[mt] = __builtin_amdgcn_mfma_f32_16x16x32_bf16(ah, wf, acc[mt], 0, 0, 0);
                acc[mt] = __builtin_amdgcn_mfma_f32_16x16x32_bf16(al, wf, acc[mt], 0, 0, 0);
            }
        }

        if (kt + 1 < nt) {
            write_lds((kt + 1) & 1);
            __syncthreads();
        }
    }

    float* Pp = Cpart + (size_t)blockIdx.y * 64 * N;
    int col = n0 + wrow;
#pragma unroll
    for (int mt = 0; mt < 4; mt++) {
#pragma unroll
        for (int r = 0; r < 4; r++) {
            int row = mt * 16 + lk * 4 + r;
            Pp[(size_t)row * N + col] = acc[mt][r];
        }
    }
}

// ---------------------------------------------------------------------------
// GRU gate combine: 8 K-split partials of fused [gi | gh] + biases -> h_out
__global__ __launch_bounds__(256) void gru_combine_k(
    const float* __restrict__ P, const float* __restrict__ b_ih,
    const float* __restrict__ b_hh, const float* __restrict__ hprev,
    float* __restrict__ hout) {
    int idx = blockIdx.x * 256 + threadIdx.x;  // 65536
    int b = idx >> 10, j = idx & 1023;
    const size_t stride = (size_t)64 * N_GATES;
    const float* rowp = P + (size_t)b * N_GATES;

    float ir = 0.f, iz = 0.f, in_ = 0.f, hr = 0.f, hz = 0.f, hn = 0.f;
#pragma unroll
    for (int kc = 0; kc < KSPL_GRU; kc++) {
        const float* p = rowp + kc * stride;
        ir += p[j];        iz += p[j + 1024];        in_ += p[j + 2048];
        hr += p[3072 + j]; hz += p[3072 + j + 1024]; hn += p[3072 + j + 2048];
    }
    ir += b_ih[j]; iz += b_ih[j + 1024]; in_ += b_ih[j + 2048];
    hr += b_hh[j]; hz += b_hh[j + 1024]; hn += b_hh[j + 2048];

    float r = 1.f / (1.f + __expf(-(ir + hr)));
    float z = 1.f / (1.f + __expf(-(iz + hz)));
    float n = tanhf(in_ + r * hn);
    float hp = hprev[idx];
    hout[idx] = (1.f - z) * n + z * hp;
}

// ---------------------------------------------------------------------------
// Fused attention pass 1 (unchanged)
__global__ __launch_bounds__(256) void attn_pass1(
    const float* __restrict__ rnn, const float* __restrict__ enc,
    float* __restrict__ scores, float* __restrict__ ctxPart,
    float* __restrict__ chunkMax) {
    __shared__ float lm[4];
    __shared__ float lc[4][1024];

    int bid = blockIdx.x;
    int b = bid >> 4, scv = bid & 15;
    int tid = threadIdx.x;
    int w = tid >> 6, lane = tid & 63;

    const float4* rr = (const float4*)(rnn + (size_t)b * H_);
    float4 r0 = rr[0 * 64 + lane], r1 = rr[1 * 64 + lane];
    float4 r2 = rr[2 * 64 + lane], r3 = rr[3 * 64 + lane];

    float m = -FLT_MAX;
    float4 c0 = {0, 0, 0, 0}, c1 = {0, 0, 0, 0}, c2 = {0, 0, 0, 0}, c3 = {0, 0, 0, 0};

    int s0 = scv * 64 + w * 16;
    for (int si = 0; si < 16; si++) {
        int s = s0 + si;
        const float4* er = (const float4*)(enc + ((size_t)s * B_ + b) * H_);
        float4 e0 = er[0 * 64 + lane], e1 = er[1 * 64 + lane];
        float4 e2 = er[2 * 64 + lane], e3 = er[3 * 64 + lane];

        float d = e0.x * r0.x + e0.y * r0.y + e0.z * r0.z + e0.w * r0.w;
        d += e1.x * r1.x + e1.y * r1.y + e1.z * r1.z + e1.w * r1.w;
        d += e2.x * r2.x + e2.y * r2.y + e2.z * r2.z + e2.w * r2.w;
        d += e3.x * r3.x + e3.y * r3.y + e3.z * r3.z + e3.w * r3.w;
#pragma unroll
        for (int off = 32; off; off >>= 1) d += __shfl_xor(d, off, 64);
        if (lane == 0) scores[(size_t)b * S_ + s] = d;

        if (d > m) {  // wave-uniform (d identical on all lanes)
            float scale = __expf(m - d);
            c0.x *= scale; c0.y *= scale; c0.z *= scale; c0.w *= scale;
            c1.x *= scale; c1.y *= scale; c1.z *= scale; c1.w *= scale;
            c2.x *= scale; c2.y *= scale; c2.z *= scale; c2.w *= scale;
            c3.x *= scale; c3.y *= scale; c3.z *= scale; c3.w *= scale;
            m = d;
        }
        float p = __expf(d - m);
        c0.x += p * e0.x; c0.y += p * e0.y; c0.z += p * e0.z; c0.w += p * e0.w;
        c1.x += p * e1.x; c1.y += p * e1.y; c1.z += p * e1.z; c1.w += p * e1.w;
        c2.x += p * e2.x; c2.y += p * e2.y; c2.z += p * e2.z; c2.w += p * e2.w;
        c3.x += p * e3.x; c3.y += p * e3.y; c3.z += p * e3.z; c3.w += p * e3.w;
    }

    if (lane == 0) lm[w] = m;
    __syncthreads();
    float M = fmaxf(fmaxf(lm[0], lm[1]), fmaxf(lm[2], lm[3]));
    float sw = __expf(m - M);
    float4* lw = (float4*)&lc[w][0];
    float4 t;
    t.x = c0.x * sw; t.y = c0.y * sw; t.z = c0.z * sw; t.w = c0.w * sw; lw[0 * 64 + lane] = t;
    t.x = c1.x * sw; t.y = c1.y * sw; t.z = c1.z * sw; t.w = c1.w * sw; lw[1 * 64 + lane] = t;
    t.x = c2.x * sw; t.y = c2.y * sw; t.z = c2.z * sw; t.w = c2.w * sw; lw[2 * 64 + lane] = t;
    t.x = c3.x * sw; t.y = c3.y * sw; t.z = c3.z * sw; t.w = c3.w * sw; lw[3 * 64 + lane] = t;
    __syncthreads();

    float4 s4 = *(const float4*)&lc[0][tid * 4];
    float4 a1 = *(const float4*)&lc[1][tid * 4];
    float4 a2 = *(const float4*)&lc[2][tid * 4];
    float4 a3 = *(const float4*)&lc[3][tid * 4];
    s4.x += a1.x + a2.x + a3.x; s4.y += a1.y + a2.y + a3.y;
    s4.z += a1.z + a2.z + a3.z; s4.w += a1.w + a2.w + a3.w;
    *(float4*)&ctxPart[(size_t)bid * H_ + tid * 4] = s4;
    if (tid == 0) chunkMax[bid] = M;
}

// ---------------------------------------------------------------------------
// Attention pass 2 (unchanged)
__global__ __launch_bounds__(256) void attn_pass2(
    const float* __restrict__ scores, const float* __restrict__ chunkMax,
    const float* __restrict__ ctxPart, const float* __restrict__ rnn,
    float* __restrict__ attn, float* __restrict__ concat_in) {
    __shared__ float red[256];
    int b = blockIdx.x, tid = threadIdx.x;

    float v[4];
#pragma unroll
    for (int q = 0; q < 4; q++) v[q] = scores[(size_t)b * S_ + q * 256 + tid];
    float mx = fmaxf(fmaxf(v[0], v[1]), fmaxf(v[2], v[3]));
    red[tid] = mx; __syncthreads();
    for (int s = 128; s; s >>= 1) {
        if (tid < s) red[tid] = fmaxf(red[tid], red[tid + s]);
        __syncthreads();
    }
    float M = red[0]; __syncthreads();
    float e[4], sum = 0.f;
#pragma unroll
    for (int q = 0; q < 4; q++) { e[q] = __expf(v[q] - M); sum += e[q]; }
    red[tid] = sum; __syncthreads();
    for (int s = 128; s; s >>= 1) {
        if (tid < s) red[tid] += red[tid + s];
        __syncthreads();
    }
    float inv = 1.f / red[0];
#pragma unroll
    for (int q = 0; q < 4; q++) attn[(size_t)b * S_ + q * 256 + tid] = e[q] * inv;

    float4 acc = {0, 0, 0, 0};
#pragma unroll
    for (int c = 0; c < 16; c++) {
        float scl = __expf(chunkMax[b * 16 + c] - M);
        float4 part = *(const float4*)&ctxPart[((size_t)b * 16 + c) * H_ + tid * 4];
        acc.x += scl * part.x; acc.y += scl * part.y;
        acc.z += scl * part.z; acc.w += scl * part.w;
    }
    acc.x *= inv; acc.y *= inv; acc.z *= inv; acc.w *= inv;
    *(float4*)&concat_in[(size_t)b * 2048 + 1024 + tid * 4] = acc;
    *(float4*)&concat_in[(size_t)b * 2048 + tid * 4] =
        *(const float4*)&rnn[(size_t)b * H_ + tid * 4];
}

// ---------------------------------------------------------------------------
// Concat combine: sum 16 K-split partials + bias, tanh; emit bf16 hi/lo.
__global__ __launch_bounds__(256) void concat_combine_k(const float* __restrict__ P,
                                                        const float* __restrict__ bias,
                                                        ushort* __restrict__ Ahi,
                                                        ushort* __restrict__ Alo) {
    int idx = blockIdx.x * 256 + threadIdx.x;  // 65536
    int b = idx >> 10, h = idx & 1023;
    float s = 0.f;
#pragma unroll
    for (int kc = 0; kc < KSPL_CAT; kc++) s += P[(size_t)kc * 65536 + (size_t)b * H_ + h];
    float v = tanhf(s + bias[h]);
    ushort hi, lo;
    split_bf16(v, hi, lo);
    Ahi[idx] = hi;
    Alo[idx] = lo;
}

// ---------------------------------------------------------------------------
// Output GEMM v6: out[64][V] = (Ahi+Alo)[64][1024] x bf16(W[V][1024])^T + b.
// KEY: W is read as CONTIGUOUS full rows (32 rows x 2KB per phase = 64KB
// sequential region per block-phase) -- the only access shape that delivers
// full HBM BW (prior variants' 4KB-strided 64-256B chunks capped at ~20%).
// Per phase: stage 32 rows x 512 k as bf16 into 32 KB LDS, one barrier, then
// a barrier-free compute loop (W from LDS, A hi/lo direct from L2 with
// 1-deep prefetch). Grid 1572 (6.1 blk/CU), LDS 32 KB -> ~4-5 resident.
// XOR-swizzled slots: all LDS ops hit the 8-round b128 minimum.
__global__ __launch_bounds__(256) void gemm_out_bf16(
    const ushort* __restrict__ Ahi, const ushort* __restrict__ Alo,
    const float* __restrict__ W, const float* __restrict__ bias,
    float* __restrict__ out) {
    __shared__ ushort WtL[32 * 512];  // 32 KB: [32 rows][512 bf16]

    int tid = threadIdx.x;
    int w = tid >> 6, l = tid & 63;
    int lr = l & 15;  // fragment row (A) / col (B) within 16-tile
    int lk = l >> 4;  // k-subgroup 0..3

    int n0 = blockIdx.x * 32;

    // staging map: thread -> (W row srow 0..31, chunk sc 0..7 of 64 floats)
    int srow = tid >> 3;
    int sc = tid & 7;
    int wrg = n0 + srow;
    const float* Wsrc = W + (size_t)(wrg < V_ ? wrg : 0) * H_;

    union SV { short8v v; ushort u[8]; };

    f32x4 acc[2];
    acc[0] = (f32x4){0.f, 0.f, 0.f, 0.f};
    acc[1] = (f32x4){0.f, 0.f, 0.f, 0.f};

    const ushort* Ah = Ahi + (size_t)(w * 16 + lr) * H_;
    const ushort* Al = Alo + (size_t)(w * 16 + lr) * H_;

    for (int ph = 0; ph < 2; ph++) {
        int kb0 = ph * 512;

        // ---- stage: 32 rows x 512 floats, contiguous 256B runs per thread ----
        {
            const float* src = Wsrc + kb0 + sc * 64;
            int rbase = srow * 512;
            int r7 = srow & 7;
#pragma unroll
            for (int j = 0; j < 8; j++) {
                float4 f0 = *(const float4*)&src[j * 8];
                float4 f1 = *(const float4*)&src[j * 8 + 4];
                SV p;
                const float* a = (const float*)&f0;
                const float* b = (const float*)&f1;
#pragma unroll
                for (int i = 0; i < 4; i++) {
                    p.u[i] = rnd_bf16(a[i]);
                    p.u[i + 4] = rnd_bf16(b[i]);
                }
                int slot = sc * 8 + j;
                *(short8v*)&WtL[rbase + ((slot ^ r7) << 3)] = p.v;
            }
        }
        __syncthreads();

        // ---- compute: 8 kt, barrier-free, A prefetched 1 deep ----
        int kb = kb0 + lk * 8;
        short8v ah0 = *(const short8v*)&Ah[kb];
        short8v al0 = *(const short8v*)&Al[kb];
        short8v ah1 = *(const short8v*)&Ah[kb + 32];
        short8v al1 = *(const short8v*)&Al[kb + 32];

        for (int kt = 0; kt < 8; kt++) {
            short8v nah0, nal0, nah1, nal1;
            if (kt + 1 < 8) {
                int nkb = kb0 + (kt + 1) * 64 + lk * 8;
                nah0 = *(const short8v*)&Ah[nkb];
                nal0 = *(const short8v*)&Al[nkb];
                nah1 = *(const short8v*)&Ah[nkb + 32];
                nal1 = *(const short8v*)&Al[nkb + 32];
            }

#pragma unroll
            for (int nt = 0; nt < 2; nt++) {
                int wr = nt * 16 + lr;
                int r7 = wr & 7;
                int sb = kt * 8;
                short8v wf0 = *(const short8v*)&WtL[wr * 512 + (((sb + lk) ^ r7) << 3)];
                short8v wf1 = *(const short8v*)&WtL[wr * 512 + (((sb + 4 + lk) ^ r7) << 3)];
                acc[nt] = __builtin_amdgcn_mfma_f32_16x16x32_bf16(ah0, wf0, acc[nt], 0, 0, 0);
                acc[nt] = __builtin_amdgcn_mfma_f32_16x16x32_bf16(al0, wf0, acc[nt], 0, 0, 0);
                acc[nt] = __builtin_amdgcn_mfma_f32_16x16x32_bf16(ah1, wf1, acc[nt], 0, 0, 0);
                acc[nt] = __builtin_amdgcn_mfma_f32_16x16x32_bf16(al1, wf1, acc[nt], 0, 0, 0);
            }

            ah0 = nah0; al0 = nal0; ah1 = nah1; al1 = nal1;
        }
        __syncthreads();  // readers done before restage / epilogue overlay
    }

    // ---- epilogue: LDS bounce (overlays WtL, 8 KB) for coalesced stores ----
    // acc[nt][r] -> row = w*16 + lk*4 + r, col = n0 + nt*16 + lr
    float* et = (float*)&WtL[0];  // [64 rows][32 cols]
#pragma unroll
    for (int nt = 0; nt < 2; nt++) {
#pragma unroll
        for (int r = 0; r < 4; r++) {
            int row = w * 16 + lk * 4 + r;
            et[row * 32 + nt * 16 + lr] = acc[nt][r];
        }
    }
    __syncthreads();

    int col = tid & 31;  // block-local out col
    int rg = tid >> 5;   // 8 row groups of 8
    int gc = n0 + col;
    if (gc < V_) {
        float b = bias[gc];
#pragma unroll
        for (int rr = 0; rr < 8; rr++) {
            int row = rg * 8 + rr;
            out[(size_t)row * V_ + gc] = et[row * 32 + col] + b;
        }
    }
}

// ---------------------------------------------------------------------------
extern "C" void kernel_launch(void* const* d_in, const int* in_sizes, int n_in,
                              void* d_out, int out_size, void* d_ws, size_t ws_size,
                              hipStream_t stream) {
    const int* seq = (const int*)d_in[0];
    const float* last_hidden = (const float*)d_in[1];
    const float* enc = (const float*)d_in[2];
    const float* emb = (const float*)d_in[3];
    const float* w_ih = (const float*)d_in[4];
    const float* w_hh = (const float*)d_in[5];
    const float* b_ih = (const float*)d_in[6];
    const float* b_hh = (const float*)d_in[7];
    const float* concat_w = (const float*)d_in[8];
    const float* concat_b = (const float*)d_in[9];
    const float* out_w = (const float*)d_in[10];
    const float* out_b = (const float*)d_in[11];

    float* out = (float*)d_out;                           // (B,V)
    float* out_hidden = out + (size_t)B_ * V_;            // (L,B,H)
    float* out_attn = out_hidden + (size_t)L_ * B_ * H_;  // (B,1,S)

    float* ws = (float*)d_ws;
    float* gatesP = ws;                    // 8*64*6144 = 3145728
    float* scores = gatesP + 3145728;      // 65536
    float* chunkMax = scores + 65536;      // 1024
    float* ctxPart = chunkMax + 1024;      // 1048576
    float* concat_in = ctxPart + 1048576;  // 131072
    float* concatP = concat_in + 131072;   // 16*64*1024 = 1048576
    ushort* Ahi = (ushort*)(concatP + 1048576);  // 65536 ushort
    ushort* Alo = Ahi + 65536;                   // 65536 ushort

    // 1+2. GRU layers (layer 0 fuses the embedding gather via seq)
    for (int l = 0; l < L_; l++) {
        const float* xl = (l == 0) ? emb : out_hidden + (size_t)(l - 1) * B_ * H_;
        const int* sq = (l == 0) ? seq : nullptr;
        const float* hl = last_hidden + (size_t)l * B_ * H_;
        gemm_bf16_lds<<<dim3(N_GATES / 64, KSPL_GRU), 256, 0, stream>>>(
            xl, sq, hl, H_,
            w_ih + (size_t)l * G3H * H_, w_hh + (size_t)l * G3H * H_, H_, G3H,
            gatesP, N_GATES, H_);
        gru_combine_k<<<256, 256, 0, stream>>>(gatesP, b_ih + (size_t)l * G3H,
                                               b_hh + (size_t)l * G3H, hl,
                                               out_hidden + (size_t)l * B_ * H_);
    }
    const float* rnn = out_hidden + (size_t)2 * B_ * H_;

    // 3. Fused attention (single enc pass) + combine/assemble
    attn_pass1<<<1024, 256, 0, stream>>>(rnn, enc, scores, ctxPart, chunkMax);
    attn_pass2<<<64, 256, 0, stream>>>(scores, chunkMax, ctxPart, rnn,
                                       out_attn, concat_in);

    // 4. Concat GEMM (K=2048, 16-way K-split) + tanh combine (+ bf16 split)
    gemm_bf16_lds<<<dim3(H_ / 64, KSPL_CAT), 256, 0, stream>>>(
        concat_in, nullptr, concat_in, 2048, concat_w, concat_w, 2048, 1 << 30,
        concatP, H_, 2048);
    concat_combine_k<<<256, 256, 0, stream>>>(concatP, concat_b, Ahi, Alo);

    // 5. Output GEMM v6: contiguous-row W staging, barrier-free compute
    gemm_out_bf16<<<VPAD / 32, 256, 0, stream>>>(Ahi, Alo, out_w, out_b, out);
}

// Round 13
// 184.453 us; speedup vs baseline: 1.1867x; 1.1867x over previous
//
#include <hip/hip_runtime.h>
#include <hip/hip_bf16.h>
#include <float.h>

#define B_ 64
#define H_ 1024
#define S_ 1024
#define V_ 50257
#define L_ 3
#define G3H 3072      // 3*H
#define N_GATES 6144  // 2*3H fused gi|gh
#define NT_K 16       // 1024 / 64 k-tiles in output GEMM
#define KSPL_GRU 8    // K-split for GRU gates GEMM
#define KSPL_CAT 16   // K-split for concat GEMM

typedef __attribute__((ext_vector_type(8))) short short8v;  // 8 bf16 (4 VGPRs)
typedef __attribute__((ext_vector_type(4))) float f32x4;    // MFMA accumulator

// round-to-nearest f32 -> bf16 bits
__device__ __forceinline__ ushort rnd_bf16(float x) {
    uint u = __float_as_uint(x);
    return (ushort)((u + 0x7fffu + ((u >> 16) & 1u)) >> 16);
}

// exact split x = hi + lo (hi = truncated bf16, lo = rounded residual)
__device__ __forceinline__ void split_bf16(float x, ushort& hi, ushort& lo) {
    uint u = __float_as_uint(x);
    uint h = u & 0xffff0000u;
    hi = (ushort)(h >> 16);
    float r = x - __uint_as_float(h);
    uint ur = __float_as_uint(r);
    lo = (ushort)((ur + 0x7fffu + ((ur >> 16) & 1u)) >> 16);
}

// ---------------------------------------------------------------------------
// Generic M=64 bf16-MFMA GEMM, all-LDS inner loop (R9-best):
// Cpart[ky][64][N] = A[64][K] x W[N][K]^T partials. A fp32 -> exact hi/lo
// bf16 split during staging; W fp32 -> rounded bf16. Dual-A/W via Nhalf.
// Optional seq row gather on A0. XOR-swizzled 16B slots, double-buffered.
__global__ __launch_bounds__(256) void gemm_bf16_lds(
    const float* __restrict__ A0, const int* __restrict__ seq,
    const float* __restrict__ A1, int lda,
    const float* __restrict__ W0, const float* __restrict__ W1, int ldw,
    int Nhalf, float* __restrict__ Cpart, int N, int K) {
    __shared__ ushort AhL[2][64 * 64];
    __shared__ ushort AlL[2][64 * 64];
    __shared__ ushort WtL[2][64 * 64];  // 48 KB total

    int tid = threadIdx.x;
    int w = tid >> 6, l = tid & 63;
    int lr = l & 15;  // A row / W row within 16-tile
    int lk = l >> 4;  // k-subgroup 0..3

    int n0 = blockIdx.x * 64;
    const float* A = A0;
    const float* W = W0;
    const int* sq = seq;
    int ncol0 = n0;
    if (n0 >= Nhalf) { A = A1; W = W1; ncol0 = n0 - Nhalf; sq = nullptr; }

    int srow = tid >> 2;  // 0..63
    int sqk = tid & 3;    // 0..3
    const float* Asrc = A + (size_t)(sq ? sq[srow] : srow) * lda;
    const float* Wsrc = W + (size_t)(ncol0 + srow) * ldw;

    int kChunk = K / gridDim.y;
    int kBeg = blockIdx.y * kChunk;
    int nt = kChunk >> 6;  // 64-k tiles

    union SV { short8v v; ushort u[8]; };

    float4 rA[4], rW[4];
    auto load_regs = [&](int kt) {
        int kb = kBeg + kt * 64 + sqk * 16;
#pragma unroll
        for (int i = 0; i < 4; i++) {
            rA[i] = *(const float4*)&Asrc[kb + i * 4];
            rW[i] = *(const float4*)&Wsrc[kb + i * 4];
        }
    };
    auto write_lds = [&](int buf) {
        int s0 = (2 * sqk) ^ (srow & 7);
        int s1 = (2 * sqk + 1) ^ (srow & 7);
        int base = srow * 64;
        SV h0, h1, l0, l1, q0, q1;
        const float* fa = (const float*)&rA[0];
        const float* fw = (const float*)&rW[0];
#pragma unroll
        for (int j = 0; j < 8; j++) {
            split_bf16(fa[j], h0.u[j], l0.u[j]);
            split_bf16(fa[8 + j], h1.u[j], l1.u[j]);
            q0.u[j] = rnd_bf16(fw[j]);
            q1.u[j] = rnd_bf16(fw[8 + j]);
        }
        *(short8v*)&AhL[buf][base + s0 * 8] = h0.v;
        *(short8v*)&AhL[buf][base + s1 * 8] = h1.v;
        *(short8v*)&AlL[buf][base + s0 * 8] = l0.v;
        *(short8v*)&AlL[buf][base + s1 * 8] = l1.v;
        *(short8v*)&WtL[buf][base + s0 * 8] = q0.v;
        *(short8v*)&WtL[buf][base + s1 * 8] = q1.v;
    };

    f32x4 acc[4];
#pragma unroll
    for (int mt = 0; mt < 4; mt++) acc[mt] = (f32x4){0.f, 0.f, 0.f, 0.f};

    load_regs(0);
    write_lds(0);
    __syncthreads();

    int wrow = w * 16 + lr;  // block-local output col
    for (int kt = 0; kt < nt; kt++) {
        if (kt + 1 < nt) load_regs(kt + 1);  // fly under compute

        int cur = kt & 1;
#pragma unroll
        for (int ks = 0; ks < 2; ks++) {
            int slot = ks * 4 + lk;
            short8v wf = *(const short8v*)&WtL[cur][wrow * 64 + ((slot ^ (wrow & 7)) << 3)];
#pragma unroll
            for (int mt = 0; mt < 4; mt++) {
                int arow = mt * 16 + lr;
                int so = (slot ^ (arow & 7)) << 3;
                short8v ah = *(const short8v*)&AhL[cur][arow * 64 + so];
                short8v al = *(const short8v*)&AlL[cur][arow * 64 + so];
                acc[mt] = __builtin_amdgcn_mfma_f32_16x16x32_bf16(ah, wf, acc[mt], 0, 0, 0);
                acc[mt] = __builtin_amdgcn_mfma_f32_16x16x32_bf16(al, wf, acc[mt], 0, 0, 0);
            }
        }

        if (kt + 1 < nt) {
            write_lds((kt + 1) & 1);
            __syncthreads();
        }
    }

    float* Pp = Cpart + (size_t)blockIdx.y * 64 * N;
    int col = n0 + wrow;
#pragma unroll
    for (int mt = 0; mt < 4; mt++) {
#pragma unroll
        for (int r = 0; r < 4; r++) {
            int row = mt * 16 + lk * 4 + r;
            Pp[(size_t)row * N + col] = acc[mt][r];
        }
    }
}

// ---------------------------------------------------------------------------
// GRU gate combine: 8 K-split partials of fused [gi | gh] + biases -> h_out
__global__ __launch_bounds__(256) void gru_combine_k(
    const float* __restrict__ P, const float* __restrict__ b_ih,
    const float* __restrict__ b_hh, const float* __restrict__ hprev,
    float* __restrict__ hout) {
    int idx = blockIdx.x * 256 + threadIdx.x;  // 65536
    int b = idx >> 10, j = idx & 1023;
    const size_t stride = (size_t)64 * N_GATES;
    const float* rowp = P + (size_t)b * N_GATES;

    float ir = 0.f, iz = 0.f, in_ = 0.f, hr = 0.f, hz = 0.f, hn = 0.f;
#pragma unroll
    for (int kc = 0; kc < KSPL_GRU; kc++) {
        const float* p = rowp + kc * stride;
        ir += p[j];        iz += p[j + 1024];        in_ += p[j + 2048];
        hr += p[3072 + j]; hz += p[3072 + j + 1024]; hn += p[3072 + j + 2048];
    }
    ir += b_ih[j]; iz += b_ih[j + 1024]; in_ += b_ih[j + 2048];
    hr += b_hh[j]; hz += b_hh[j + 1024]; hn += b_hh[j + 2048];

    float r = 1.f / (1.f + __expf(-(ir + hr)));
    float z = 1.f / (1.f + __expf(-(iz + hz)));
    float n = tanhf(in_ + r * hn);
    float hp = hprev[idx];
    hout[idx] = (1.f - z) * n + z * hp;
}

// ---------------------------------------------------------------------------
// Fused attention pass 1: one enc read -> raw scores + online-softmax context
// partials. grid = 64 b * 16 sc; 4 waves/block, each wave owns 16 s rows.
__global__ __launch_bounds__(256) void attn_pass1(
    const float* __restrict__ rnn, const float* __restrict__ enc,
    float* __restrict__ scores, float* __restrict__ ctxPart,
    float* __restrict__ chunkMax) {
    __shared__ float lm[4];
    __shared__ float lc[4][1024];

    int bid = blockIdx.x;
    int b = bid >> 4, scv = bid & 15;
    int tid = threadIdx.x;
    int w = tid >> 6, lane = tid & 63;

    const float4* rr = (const float4*)(rnn + (size_t)b * H_);
    float4 r0 = rr[0 * 64 + lane], r1 = rr[1 * 64 + lane];
    float4 r2 = rr[2 * 64 + lane], r3 = rr[3 * 64 + lane];

    float m = -FLT_MAX;
    float4 c0 = {0, 0, 0, 0}, c1 = {0, 0, 0, 0}, c2 = {0, 0, 0, 0}, c3 = {0, 0, 0, 0};

    int s0 = scv * 64 + w * 16;
    for (int si = 0; si < 16; si++) {
        int s = s0 + si;
        const float4* er = (const float4*)(enc + ((size_t)s * B_ + b) * H_);
        float4 e0 = er[0 * 64 + lane], e1 = er[1 * 64 + lane];
        float4 e2 = er[2 * 64 + lane], e3 = er[3 * 64 + lane];

        float d = e0.x * r0.x + e0.y * r0.y + e0.z * r0.z + e0.w * r0.w;
        d += e1.x * r1.x + e1.y * r1.y + e1.z * r1.z + e1.w * r1.w;
        d += e2.x * r2.x + e2.y * r2.y + e2.z * r2.z + e2.w * r2.w;
        d += e3.x * r3.x + e3.y * r3.y + e3.z * r3.z + e3.w * r3.w;
#pragma unroll
        for (int off = 32; off; off >>= 1) d += __shfl_xor(d, off, 64);
        if (lane == 0) scores[(size_t)b * S_ + s] = d;

        if (d > m) {  // wave-uniform (d identical on all lanes)
            float scale = __expf(m - d);
            c0.x *= scale; c0.y *= scale; c0.z *= scale; c0.w *= scale;
            c1.x *= scale; c1.y *= scale; c1.z *= scale; c1.w *= scale;
            c2.x *= scale; c2.y *= scale; c2.z *= scale; c2.w *= scale;
            c3.x *= scale; c3.y *= scale; c3.z *= scale; c3.w *= scale;
            m = d;
        }
        float p = __expf(d - m);
        c0.x += p * e0.x; c0.y += p * e0.y; c0.z += p * e0.z; c0.w += p * e0.w;
        c1.x += p * e1.x; c1.y += p * e1.y; c1.z += p * e1.z; c1.w += p * e1.w;
        c2.x += p * e2.x; c2.y += p * e2.y; c2.z += p * e2.z; c2.w += p * e2.w;
        c3.x += p * e3.x; c3.y += p * e3.y; c3.z += p * e3.z; c3.w += p * e3.w;
    }

    if (lane == 0) lm[w] = m;
    __syncthreads();
    float M = fmaxf(fmaxf(lm[0], lm[1]), fmaxf(lm[2], lm[3]));
    float sw = __expf(m - M);
    float4* lw = (float4*)&lc[w][0];
    float4 t;
    t.x = c0.x * sw; t.y = c0.y * sw; t.z = c0.z * sw; t.w = c0.w * sw; lw[0 * 64 + lane] = t;
    t.x = c1.x * sw; t.y = c1.y * sw; t.z = c1.z * sw; t.w = c1.w * sw; lw[1 * 64 + lane] = t;
    t.x = c2.x * sw; t.y = c2.y * sw; t.z = c2.z * sw; t.w = c2.w * sw; lw[2 * 64 + lane] = t;
    t.x = c3.x * sw; t.y = c3.y * sw; t.z = c3.z * sw; t.w = c3.w * sw; lw[3 * 64 + lane] = t;
    __syncthreads();

    float4 s4 = *(const float4*)&lc[0][tid * 4];
    float4 a1 = *(const float4*)&lc[1][tid * 4];
    float4 a2 = *(const float4*)&lc[2][tid * 4];
    float4 a3 = *(const float4*)&lc[3][tid * 4];
    s4.x += a1.x + a2.x + a3.x; s4.y += a1.y + a2.y + a3.y;
    s4.z += a1.z + a2.z + a3.z; s4.w += a1.w + a2.w + a3.w;
    *(float4*)&ctxPart[(size_t)bid * H_ + tid * 4] = s4;
    if (tid == 0) chunkMax[bid] = M;
}

// ---------------------------------------------------------------------------
// Attention pass 2 (per b): global softmax -> attn output, rescale+sum chunk
// contexts, assemble concat_in = [rnn | ctx].
__global__ __launch_bounds__(256) void attn_pass2(
    const float* __restrict__ scores, const float* __restrict__ chunkMax,
    const float* __restrict__ ctxPart, const float* __restrict__ rnn,
    float* __restrict__ attn, float* __restrict__ concat_in) {
    __shared__ float red[256];
    int b = blockIdx.x, tid = threadIdx.x;

    float v[4];
#pragma unroll
    for (int q = 0; q < 4; q++) v[q] = scores[(size_t)b * S_ + q * 256 + tid];
    float mx = fmaxf(fmaxf(v[0], v[1]), fmaxf(v[2], v[3]));
    red[tid] = mx; __syncthreads();
    for (int s = 128; s; s >>= 1) {
        if (tid < s) red[tid] = fmaxf(red[tid], red[tid + s]);
        __syncthreads();
    }
    float M = red[0]; __syncthreads();
    float e[4], sum = 0.f;
#pragma unroll
    for (int q = 0; q < 4; q++) { e[q] = __expf(v[q] - M); sum += e[q]; }
    red[tid] = sum; __syncthreads();
    for (int s = 128; s; s >>= 1) {
        if (tid < s) red[tid] += red[tid + s];
        __syncthreads();
    }
    float inv = 1.f / red[0];
#pragma unroll
    for (int q = 0; q < 4; q++) attn[(size_t)b * S_ + q * 256 + tid] = e[q] * inv;

    float4 acc = {0, 0, 0, 0};
#pragma unroll
    for (int c = 0; c < 16; c++) {
        float scl = __expf(chunkMax[b * 16 + c] - M);
        float4 part = *(const float4*)&ctxPart[((size_t)b * 16 + c) * H_ + tid * 4];
        acc.x += scl * part.x; acc.y += scl * part.y;
        acc.z += scl * part.z; acc.w += scl * part.w;
    }
    acc.x *= inv; acc.y *= inv; acc.z *= inv; acc.w *= inv;
    *(float4*)&concat_in[(size_t)b * 2048 + 1024 + tid * 4] = acc;
    *(float4*)&concat_in[(size_t)b * 2048 + tid * 4] =
        *(const float4*)&rnn[(size_t)b * H_ + tid * 4];
}

// ---------------------------------------------------------------------------
// Concat combine: sum 16 K-split partials + bias, tanh; emit bf16 hi/lo.
__global__ __launch_bounds__(256) void concat_combine_k(const float* __restrict__ P,
                                                        const float* __restrict__ bias,
                                                        ushort* __restrict__ Ahi,
                                                        ushort* __restrict__ Alo) {
    int idx = blockIdx.x * 256 + threadIdx.x;  // 65536
    int b = idx >> 10, h = idx & 1023;
    float s = 0.f;
#pragma unroll
    for (int kc = 0; kc < KSPL_CAT; kc++) s += P[(size_t)kc * 65536 + (size_t)b * H_ + h];
    float v = tanhf(s + bias[h]);
    ushort hi, lo;
    split_bf16(v, hi, lo);
    Ahi[idx] = hi;
    Alo[idx] = lo;
}

// ---------------------------------------------------------------------------
// Output GEMM v3 (R9-best): out[64][V] = (Ahi+Alo)[64][1024] x bf16(W)^T + b.
// All-LDS inner loop (A hi/lo AND W staged; W converted to bf16 at staging),
// XOR-swizzled 16B slots, double-buffered, one barrier pair per 64-k tile,
// coalesced epilogue via LDS bounce.
__global__ __launch_bounds__(256) void gemm_out_bf16(
    const ushort* __restrict__ Ahi, const ushort* __restrict__ Alo,
    const float* __restrict__ W, const float* __restrict__ bias,
    float* __restrict__ out) {
    __shared__ ushort AhL[2][64 * 64];
    __shared__ ushort AlL[2][64 * 64];
    __shared__ ushort WtL[2][64 * 64];

    int tid = threadIdx.x;
    int w = tid >> 6, l = tid & 63;
    int lr = l & 15;
    int lk = l >> 4;

    int n0 = blockIdx.x * 64;

    int srow = tid >> 2;
    int sqk = tid & 3;
    int wrow_g = n0 + srow;
    const float* Wsrc = W + (size_t)(wrow_g < V_ ? wrow_g : 0) * H_;

    union SV { short8v v; ushort u[8]; };

    short8v rAh0, rAh1, rAl0, rAl1;
    float4 rW[4];

    auto load_regs = [&](int kt) {
        int kb = kt * 64 + sqk * 16;
        rAh0 = *(const short8v*)&Ahi[(size_t)srow * H_ + kb];
        rAh1 = *(const short8v*)&Ahi[(size_t)srow * H_ + kb + 8];
        rAl0 = *(const short8v*)&Alo[(size_t)srow * H_ + kb];
        rAl1 = *(const short8v*)&Alo[(size_t)srow * H_ + kb + 8];
#pragma unroll
        for (int i = 0; i < 4; i++) rW[i] = *(const float4*)&Wsrc[kb + i * 4];
    };

    auto write_lds = [&](int buf) {
        int s0 = (2 * sqk) ^ (srow & 7);
        int s1 = (2 * sqk + 1) ^ (srow & 7);
        int base = srow * 64;
        *(short8v*)&AhL[buf][base + s0 * 8] = rAh0;
        *(short8v*)&AhL[buf][base + s1 * 8] = rAh1;
        *(short8v*)&AlL[buf][base + s0 * 8] = rAl0;
        *(short8v*)&AlL[buf][base + s1 * 8] = rAl1;
        SV p0, p1;
        const float* f = (const float*)&rW[0];
#pragma unroll
        for (int j = 0; j < 8; j++) {
            p0.u[j] = rnd_bf16(f[j]);
            p1.u[j] = rnd_bf16(f[8 + j]);
        }
        *(short8v*)&WtL[buf][base + s0 * 8] = p0.v;
        *(short8v*)&WtL[buf][base + s1 * 8] = p1.v;
    };

    f32x4 acc[4];
#pragma unroll
    for (int mt = 0; mt < 4; mt++) acc[mt] = (f32x4){0.f, 0.f, 0.f, 0.f};

    load_regs(0);
    write_lds(0);
    __syncthreads();

    int wrow = w * 16 + lr;
    for (int kt = 0; kt < NT_K; kt++) {
        if (kt + 1 < NT_K) load_regs(kt + 1);

        int cur = kt & 1;
#pragma unroll
        for (int ks = 0; ks < 2; ks++) {
            int slot = ks * 4 + lk;
            short8v wf = *(const short8v*)&WtL[cur][wrow * 64 + ((slot ^ (wrow & 7)) << 3)];
#pragma unroll
            for (int mt = 0; mt < 4; mt++) {
                int arow = mt * 16 + lr;
                int so = (slot ^ (arow & 7)) << 3;
                short8v ah = *(const short8v*)&AhL[cur][arow * 64 + so];
                short8v al = *(const short8v*)&AlL[cur][arow * 64 + so];
                acc[mt] = __builtin_amdgcn_mfma_f32_16x16x32_bf16(ah, wf, acc[mt], 0, 0, 0);
                acc[mt] = __builtin_amdgcn_mfma_f32_16x16x32_bf16(al, wf, acc[mt], 0, 0, 0);
            }
        }

        if (kt + 1 < NT_K) {
            write_lds((kt + 1) & 1);
            __syncthreads();
        }
    }

    __syncthreads();
    float* et = (float*)&AhL[0][0];
#pragma unroll
    for (int mt = 0; mt < 4; mt++) {
#pragma unroll
        for (int r = 0; r < 4; r++) {
            int row = mt * 16 + lk * 4 + r;
            et[row * 64 + wrow] = acc[mt][r];
        }
    }
    __syncthreads();

    int col = tid & 63;
    int gc = n0 + col;
    int rg = tid >> 6;
    if (gc < V_) {
        float b = bias[gc];
#pragma unroll
        for (int rr = 0; rr < 16; rr++) {
            int orow = rg * 16 + rr;
            out[(size_t)orow * V_ + gc] = et[orow * 64 + col] + b;
        }
    }
}

// ---------------------------------------------------------------------------
extern "C" void kernel_launch(void* const* d_in, const int* in_sizes, int n_in,
                              void* d_out, int out_size, void* d_ws, size_t ws_size,
                              hipStream_t stream) {
    const int* seq = (const int*)d_in[0];
    const float* last_hidden = (const float*)d_in[1];
    const float* enc = (const float*)d_in[2];
    const float* emb = (const float*)d_in[3];
    const float* w_ih = (const float*)d_in[4];
    const float* w_hh = (const float*)d_in[5];
    const float* b_ih = (const float*)d_in[6];
    const float* b_hh = (const float*)d_in[7];
    const float* concat_w = (const float*)d_in[8];
    const float* concat_b = (const float*)d_in[9];
    const float* out_w = (const float*)d_in[10];
    const float* out_b = (const float*)d_in[11];

    float* out = (float*)d_out;                           // (B,V)
    float* out_hidden = out + (size_t)B_ * V_;            // (L,B,H)
    float* out_attn = out_hidden + (size_t)L_ * B_ * H_;  // (B,1,S)

    float* ws = (float*)d_ws;
    float* gatesP = ws;                    // 8*64*6144 = 3145728
    float* scores = gatesP + 3145728;      // 65536
    float* chunkMax = scores + 65536;      // 1024
    float* ctxPart = chunkMax + 1024;      // 1048576
    float* concat_in = ctxPart + 1048576;  // 131072
    float* concatP = concat_in + 131072;   // 16*64*1024 = 1048576
    ushort* Ahi = (ushort*)(concatP + 1048576);  // 65536 ushort
    ushort* Alo = Ahi + 65536;                   // 65536 ushort

    // 1+2. GRU layers (layer 0 fuses the embedding gather via seq)
    for (int l = 0; l < L_; l++) {
        const float* xl = (l == 0) ? emb : out_hidden + (size_t)(l - 1) * B_ * H_;
        const int* sq = (l == 0) ? seq : nullptr;
        const float* hl = last_hidden + (size_t)l * B_ * H_;
        gemm_bf16_lds<<<dim3(N_GATES / 64, KSPL_GRU), 256, 0, stream>>>(
            xl, sq, hl, H_,
            w_ih + (size_t)l * G3H * H_, w_hh + (size_t)l * G3H * H_, H_, G3H,
            gatesP, N_GATES, H_);
        gru_combine_k<<<256, 256, 0, stream>>>(gatesP, b_ih + (size_t)l * G3H,
                                               b_hh + (size_t)l * G3H, hl,
                                               out_hidden + (size_t)l * B_ * H_);
    }
    const float* rnn = out_hidden + (size_t)2 * B_ * H_;

    // 3. Fused attention (single enc pass) + combine/assemble
    attn_pass1<<<1024, 256, 0, stream>>>(rnn, enc, scores, ctxPart, chunkMax);
    attn_pass2<<<64, 256, 0, stream>>>(scores, chunkMax, ctxPart, rnn,
                                       out_attn, concat_in);

    // 4. Concat GEMM (K=2048, 16-way K-split) + tanh combine (+ bf16 split)
    gemm_bf16_lds<<<dim3(H_ / 64, KSPL_CAT), 256, 0, stream>>>(
        concat_in, nullptr, concat_in, 2048, concat_w, concat_w, 2048, 1 << 30,
        concatP, H_, 2048);
    concat_combine_k<<<256, 256, 0, stream>>>(concatP, concat_b, Ahi, Alo);

    // 5. Output GEMM v3: all-LDS inner loop, coalesced epilogue
    gemm_out_bf16<<<(V_ + 63) / 64, 256, 0, stream>>>(Ahi, Alo, out_w, out_b, out);
}